// Round 3
// baseline (396.282 us; speedup 1.0000x reference)
//
#include <hip/hip_runtime.h>

#define NUM_E 8
#define N_TOK 8192
#define DIM 1024

typedef __attribute__((ext_vector_type(8))) short short8;
typedef __attribute__((ext_vector_type(4))) float f32x4;

// fp32 -> bf16 round-to-nearest-even
__device__ __forceinline__ unsigned short f2bf(float f) {
  unsigned int u = __float_as_uint(f);
  u = (u + 0x7fffu + ((u >> 16) & 1u)) >> 16;
  return (unsigned short)u;
}

// async global->LDS, 16B per lane. Global addr is per-lane; LDS dest is
// wave-uniform base + lane*16 (m104/m108 semantics).
__device__ __forceinline__ void async16(const unsigned short* g, unsigned short* l) {
  __builtin_amdgcn_global_load_lds((const __attribute__((address_space(1))) void*)g,
                                   (__attribute__((address_space(3))) void*)l,
                                   16, 0, 0);
}

// ---------------- prep: fused W-transpose-convert + gating ----------------
__global__ __launch_bounds__(256) void prep_kernel(
    const float* __restrict__ W1, const float* __restrict__ W2,
    unsigned short* __restrict__ W1T, unsigned short* __restrict__ W2T,
    const float* __restrict__ x, const float* __restrict__ Wg,
    const float* __restrict__ bg, int* __restrict__ tok_top,
    float2* __restrict__ tok_wts, unsigned short* __restrict__ xb) {
  __shared__ float s[64][65];
  if (blockIdx.x < 4096) {
    const int bx  = blockIdx.x;          // 16 mats * 16 ktiles * 16 ntiles
    const int mat = bx >> 8;
    const int tk  = (bx >> 4) & 15;
    const int tn  = bx & 15;
    const float* src;
    unsigned short* dst;
    if (mat < 8) { src = W1 + (size_t)mat * (DIM * DIM); dst = W1T + (size_t)mat * (DIM * DIM); }
    else         { src = W2 + (size_t)(mat - 8) * (DIM * DIM); dst = W2T + (size_t)(mat - 8) * (DIM * DIM); }
    const int k0 = tk * 64, n0 = tn * 64;
    const int t = threadIdx.x;
    {
      const int rr = t >> 4;
      const int c4 = (t & 15) * 4;
#pragma unroll
      for (int i = 0; i < 4; ++i) {
        const int k = i * 16 + rr;
        float4 v = *(const float4*)&src[(size_t)(k0 + k) * DIM + n0 + c4];
        s[c4 + 0][k] = v.x; s[c4 + 1][k] = v.y;
        s[c4 + 2][k] = v.z; s[c4 + 3][k] = v.w;
      }
    }
    __syncthreads();
    {
      const int kq = (t & 7) * 8;
      const int nn = t >> 3;
#pragma unroll
      for (int r = 0; r < 2; ++r) {
        const int n = r * 32 + nn;
        union { unsigned short us[8]; uint4 v; } o;
#pragma unroll
        for (int j = 0; j < 8; ++j) o.us[j] = f2bf(s[n][kq + j]);
        *(uint4*)(dst + (size_t)(n0 + n) * DIM + k0 + kq) = o.v;
      }
    }
  } else {
    const int wave = threadIdx.x >> 6;
    const int lane = threadIdx.x & 63;
    const int n = (blockIdx.x - 4096) * 4 + wave;
    const float4* xr = (const float4*)(x + (size_t)n * DIM);
    unsigned short* xbr = xb + (size_t)n * DIM;
    float acc[NUM_E];
#pragma unroll
    for (int e = 0; e < NUM_E; ++e) acc[e] = 0.f;
#pragma unroll
    for (int it = 0; it < 4; ++it) {
      float4 xv = xr[it * 64 + lane];
      const float4* wr = (const float4*)Wg + (size_t)(it * 256 + lane * 4) * 2;
      float xs[4] = {xv.x, xv.y, xv.z, xv.w};
      union { unsigned short u[4]; uint2 v; } oo;
      oo.u[0] = f2bf(xv.x); oo.u[1] = f2bf(xv.y);
      oo.u[2] = f2bf(xv.z); oo.u[3] = f2bf(xv.w);
      *(uint2*)(xbr + it * 256 + lane * 4) = oo.v;
#pragma unroll
      for (int dd = 0; dd < 4; ++dd) {
        float4 wa = wr[dd * 2 + 0];
        float4 wb = wr[dd * 2 + 1];
        acc[0] += xs[dd] * wa.x; acc[1] += xs[dd] * wa.y;
        acc[2] += xs[dd] * wa.z; acc[3] += xs[dd] * wa.w;
        acc[4] += xs[dd] * wb.x; acc[5] += xs[dd] * wb.y;
        acc[6] += xs[dd] * wb.z; acc[7] += xs[dd] * wb.w;
      }
    }
#pragma unroll
    for (int e = 0; e < NUM_E; ++e)
#pragma unroll
      for (int off = 32; off > 0; off >>= 1)
        acc[e] += __shfl_down(acc[e], off);
    if (lane == 0) {
      float p[NUM_E];
      float mx = -1e30f;
#pragma unroll
      for (int e = 0; e < NUM_E; ++e) { p[e] = acc[e] + bg[e]; mx = fmaxf(mx, p[e]); }
      float ss = 0.f;
#pragma unroll
      for (int e = 0; e < NUM_E; ++e) { p[e] = expf(p[e] - mx); ss += p[e]; }
      float inv = 1.f / ss;
      int i0 = 0;
#pragma unroll
      for (int e = 1; e < NUM_E; ++e) if (p[e] > p[i0]) i0 = e;
      int i1 = (i0 == 0) ? 1 : 0;
#pragma unroll
      for (int e = 0; e < NUM_E; ++e) if (e != i0 && p[e] > p[i1]) i1 = e;
      tok_top[n] = i0 | (i1 << 8);
      tok_wts[n] = make_float2(p[i0] * inv, p[i1] * inv);
    }
  }
}

// gate2: one block per expert; block-wide exclusive scan compacts token lists.
__global__ __launch_bounds__(1024) void gate2_kernel(const int* __restrict__ tok_top,
                                                     const float2* __restrict__ tok_wts,
                                                     int* __restrict__ counts,
                                                     int* __restrict__ tok_idx,
                                                     float* __restrict__ tok_w) {
  const int e = blockIdx.x;
  const int t = threadIdx.x;
  const int lane = t & 63;
  const int wave = t >> 6;
  __shared__ int wsum[16];
  __shared__ int blocktot;
  int match[8];
  float w[8];
  int cnt = 0;
#pragma unroll
  for (int j = 0; j < 8; ++j) {
    int n = t * 8 + j;
    int top = tok_top[n];
    float2 ww = tok_wts[n];
    bool m0 = (top & 0xff) == e;
    bool m1 = ((top >> 8) & 0xff) == e;
    match[j] = (m0 || m1) ? 1 : 0;
    w[j] = m0 ? ww.x : ww.y;
    cnt += match[j];
  }
  int inc = cnt;
#pragma unroll
  for (int off = 1; off < 64; off <<= 1) {
    int v = __shfl_up(inc, off);
    if (lane >= off) inc += v;
  }
  if (lane == 63) wsum[wave] = inc;
  __syncthreads();
  if (t < 16) {
    int v = wsum[t];
    int s = v;
#pragma unroll
    for (int off = 1; off < 16; off <<= 1) {
      int u = __shfl_up(s, off);
      if (lane >= off) s += u;
    }
    wsum[t] = s - v;
    if (t == 15) blocktot = s;
  }
  __syncthreads();
  int slot = wsum[wave] + inc - cnt;
#pragma unroll
  for (int j = 0; j < 8; ++j) {
    if (match[j]) {
      tok_idx[e * N_TOK + slot] = t * 8 + j;
      tok_w[e * N_TOK + slot] = w[j];
      slot++;
    }
  }
  if (t == 0) counts[e] = blocktot;
}

// ---------------- expert GEMMs: 256x256, 4-phase/K-tile schedule ----------------
// R7 = R6's structural goal with the failure modes removed:
//  * static 128KB LDS (no dynamic-LDS attribute dependence)
//  * fragment-matched chunk layout (R4's, measured 0 bank conflicts) scaled to
//    BM=BN=256 / BK=64 -- ds_read addr is always lane*16B within a chunk; no swizzle.
//  * quadrant-scheduled MFMA: per phase 4-12 ds_read_b128 + 16 MFMA; fragment
//    working set 64 VGPR (not 96), total ~230 -> no spill at launch_bounds(512,1).
//  * per phase: BAR; lgkmcnt(0); sched_barrier(0) [rule #18]; setprio(1) MFMA
//    setprio(0); BAR.  One vmcnt(0) per K-tile after the last quadrant: the 8
//    prefetch loads issued in ph1/ph2 have ~3 MFMA phases of cover and nothing
//    younger is in flight (2-deep dbuf), so vmcnt(0) is exact, not a drain.
//  * prefetch k-index clamped (no OOB reads ever issued).
// LDS map (shorts): A chunk(buf,kh,rg) = buf*16384 + kh*8192 + rg*512 ; B at +32768.
// Chunk = 16 rows x 32 k, stored [quad(k8)][row16][8k] == lane-linear for both
// async16 staging and ds_read_b128 fragments.

#define BAR()    __builtin_amdgcn_s_barrier()
#define SCHED0() __builtin_amdgcn_sched_barrier(0)
#define LGKM0()  { asm volatile("s_waitcnt lgkmcnt(0)" ::: "memory"); SCHED0(); }
#define VMC0()   { asm volatile("s_waitcnt vmcnt(0)" ::: "memory"); SCHED0(); }

#define STAGE_A(BUFB, KT) { \
  async16(A_src + aOff0 + (KT) * 64,      sAB + (BUFB) + stg0); \
  async16(A_src + aOff1 + (KT) * 64,      sAB + (BUFB) + stg1); \
  async16(A_src + aOff0 + (KT) * 64 + 32, sAB + (BUFB) + 8192 + stg0); \
  async16(A_src + aOff1 + (KT) * 64 + 32, sAB + (BUFB) + 8192 + stg1); }

#define STAGE_B(BUFB, KT) { \
  async16(wTe + bOff0 + (KT) * 64,      sAB + 32768 + (BUFB) + stg0); \
  async16(wTe + bOff1 + (KT) * 64,      sAB + 32768 + (BUFB) + stg1); \
  async16(wTe + bOff0 + (KT) * 64 + 32, sAB + 32768 + (BUFB) + 8192 + stg0); \
  async16(wTe + bOff1 + (KT) * 64 + 32, sAB + 32768 + (BUFB) + 8192 + stg1); }

#define DSRA(BUFB, MH) { \
  _Pragma("unroll") \
  for (int mi = 0; mi < 4; ++mi) { \
    a[mi][0] = *(const short8*)(sAB + (BUFB) + rdA + ((MH) * 4 + mi) * 512); \
    a[mi][1] = *(const short8*)(sAB + (BUFB) + 8192 + rdA + ((MH) * 4 + mi) * 512); \
  } }

#define DSRB(BUFB, NH, DST) { \
  _Pragma("unroll") \
  for (int ni = 0; ni < 2; ++ni) { \
    DST[ni][0] = *(const short8*)(sAB + (BUFB) + rdB + ((NH) * 2 + ni) * 512); \
    DST[ni][1] = *(const short8*)(sAB + (BUFB) + 8192 + rdB + ((NH) * 2 + ni) * 512); \
  } }

#define QMFMA(MH, NH, BSET) { \
  __builtin_amdgcn_s_setprio(1); \
  _Pragma("unroll") \
  for (int mi = 0; mi < 4; ++mi) \
  _Pragma("unroll") \
  for (int ni = 0; ni < 2; ++ni) { \
    acc[(MH) * 4 + mi][(NH) * 2 + ni] = __builtin_amdgcn_mfma_f32_16x16x32_bf16( \
        a[mi][0], BSET[ni][0], acc[(MH) * 4 + mi][(NH) * 2 + ni], 0, 0, 0); \
    acc[(MH) * 4 + mi][(NH) * 2 + ni] = __builtin_amdgcn_mfma_f32_16x16x32_bf16( \
        a[mi][1], BSET[ni][1], acc[(MH) * 4 + mi][(NH) * 2 + ni], 0, 0, 0); \
  } \
  __builtin_amdgcn_s_setprio(0); }

template <bool FC1>
__global__ __launch_bounds__(512, 1) void moe_gemm_kernel(
    const unsigned short* __restrict__ A_src,  // FC1: x_bf16 ; FC2: h
    const unsigned short* __restrict__ wT,     // [E][1024 n][1024 k] bf16
    const float* __restrict__ bias,            // [E][1024]
    const int* __restrict__ counts,
    const int* __restrict__ tok_idx,           // [E][8192]
    const float* __restrict__ tok_w,           // [E][8192]
    unsigned short* __restrict__ h_out,        // FC1 dest (compacted rows)
    float* __restrict__ out)                   // FC2 dest (atomic accumulate)
{
  __shared__ unsigned short sAB[65536];  // 128 KiB

  // ---- tile table from counts (256-row m-tiles) ----
  const int y = blockIdx.y;
  int e = -1, m0 = 0, base = 0;
  {
    int at = 0, ar = 0;
#pragma unroll
    for (int i = 0; i < NUM_E; ++i) {
      int c = counts[i];
      int t = (c + 255) >> 8;
      if (y >= at && y < at + t) { e = i; m0 = (y - at) * 256; base = ar; }
      at += t; ar += t * 256;
    }
  }
  if (e < 0) return;
  const int count = counts[e];
  const int n0 = blockIdx.x * 256;

  const int tid  = threadIdx.x;
  const int w    = tid >> 6;       // wave 0..7
  const int lane = tid & 63;
  const int l15  = lane & 15;
  const int quad = lane >> 4;
  const int wr   = w >> 2;         // 0..1  M half
  const int wc   = w & 3;          // 0..3  N quarter

  // ---- staging source offsets (shorts). Wave w stages rowgroups 2w, 2w+1. ----
  unsigned aOff0, aOff1;
  if (FC1) {
    int s0 = m0 + 32 * w + l15;      s0 = s0 < count ? s0 : count - 1;
    int s1 = m0 + 32 * w + 16 + l15; s1 = s1 < count ? s1 : count - 1;
    aOff0 = (unsigned)tok_idx[e * N_TOK + s0] * DIM + quad * 8;
    aOff1 = (unsigned)tok_idx[e * N_TOK + s1] * DIM + quad * 8;
  } else {
    aOff0 = (unsigned)(base + m0 + 32 * w + l15) * DIM + quad * 8;
    aOff1 = aOff0 + 16 * DIM;
  }
  const unsigned short* wTe = wT + (size_t)e * DIM * DIM;
  const unsigned bOff0 = (unsigned)(n0 + 32 * w + l15) * DIM + quad * 8;
  const unsigned bOff1 = bOff0 + 16 * DIM;
  // wave-uniform LDS staging bases (per chunk; lanes add lane*16B in HW)
  const int stg0 = (2 * w + 0) * 512;
  const int stg1 = (2 * w + 1) * 512;
  // ds_read bases (lane-linear within chunk -> 0 bank conflicts)
  const int rdA = (wr * 8) * 512 + lane * 8;
  const int rdB = 32768 + (wc * 4) * 512 + lane * 8;

  short8 a[4][2], b01[2][2], b23[2][2];
  f32x4 acc[8][4];
  const f32x4 vzero = {0.f, 0.f, 0.f, 0.f};
#pragma unroll
  for (int i = 0; i < 8; ++i)
#pragma unroll
    for (int j = 0; j < 4; ++j) acc[i][j] = vzero;

  // ---- prologue: tile 0 into buf 0 ----
  STAGE_A(0, 0); STAGE_B(0, 0);
  VMC0(); BAR();

  // ---- main loop: 16 K-tiles of BK=64, 4 phases each ----
#pragma unroll 1
  for (int t = 0; t < 16; ++t) {
    const int pb = (t & 1) * 16384;   // current buffer
    const int qb = pb ^ 16384;        // prefetch buffer
    const int tp = (t + 1 < 16) ? t + 1 : 15;  // clamped (last prefetch unused)
    // ph1: A(MH0)+B(NH0..1) reads | prefetch A(t+1) | q(0,0)
    DSRA(pb, 0); DSRB(pb, 0, b01);
    STAGE_A(qb, tp);
    BAR(); LGKM0(); QMFMA(0, 0, b01); BAR();
    // ph2: B(NH2..3) reads | prefetch B(t+1) | q(0,1)
    DSRB(pb, 1, b23);
    STAGE_B(qb, tp);
    BAR(); LGKM0(); QMFMA(0, 1, b23); BAR();
    // ph3: A(MH1) reads | q(1,1)
    DSRA(pb, 1);
    BAR(); LGKM0(); QMFMA(1, 1, b23); BAR();
    // ph4: q(1,0) | vmcnt(0): tile t+1 landed (issued ph1/ph2, ~3 phases cover)
    BAR(); QMFMA(1, 0, b01);
    VMC0(); BAR();
  }

  // ---- epilogue ----
  float bv[4];
#pragma unroll
  for (int j = 0; j < 4; ++j)
    bv[j] = bias[e * DIM + n0 + wc * 64 + j * 16 + l15];

  // C/D layout (m89-verified): col = lane&15, row = quad*4 + reg
  if (FC1) {
#pragma unroll
    for (int mi = 0; mi < 8; ++mi) {
      const int rbase = wr * 128 + mi * 16 + quad * 4;
#pragma unroll
      for (int r = 0; r < 4; ++r) {
        const int slot = m0 + rbase + r;
        if (slot < count) {
          unsigned short* hp = h_out + (size_t)(base + slot) * DIM + n0 + wc * 64;
#pragma unroll
          for (int j = 0; j < 4; ++j) {
            float v = acc[mi][j][r] + bv[j];
            v = v > 0.f ? v : 0.f;
            hp[j * 16 + l15] = f2bf(v);
          }
        }
      }
    }
  } else {
#pragma unroll
    for (int mi = 0; mi < 8; ++mi) {
      const int rbase = wr * 128 + mi * 16 + quad * 4;
#pragma unroll
      for (int r = 0; r < 4; ++r) {
        const int slot = m0 + rbase + r;
        if (slot < count) {
          const int tok = tok_idx[e * N_TOK + slot];
          const float wgt = tok_w[e * N_TOK + slot];
          float* op = out + (size_t)tok * DIM + n0 + wc * 64;
#pragma unroll
          for (int j = 0; j < 4; ++j) {
            float v = acc[mi][j][r] + bv[j];
            atomicAdd(&op[j * 16 + l15], wgt * v);
          }
        }
      }
    }
  }
}

// ---------------- launch ----------------
// ws layout (bytes):
//   0         counts[8]
//   1024      tok_idx [8][8192] int    (256 KB)
//   263168    tok_w   [8][8192] float  (256 KB)
//   525312    x_bf16  [8192][1024]     (16 MB)
//   +16MB     W1T bf16 [8][1024][1024] (16 MB)
//   +32MB     W2T bf16                 (16 MB)
//   +48MB     h bf16, 18432 rows x1024 (36 MB)  (256-padded rows, max 18432)
//   88605696  tok_top int[8192] (32KB), tok_wts float2[8192] (64KB)

extern "C" void kernel_launch(void* const* d_in, const int* in_sizes, int n_in,
                              void* d_out, int out_size, void* d_ws, size_t ws_size,
                              hipStream_t stream) {
  const float* x  = (const float*)d_in[0];
  const float* W1 = (const float*)d_in[1];
  const float* b1 = (const float*)d_in[2];
  const float* W2 = (const float*)d_in[3];
  const float* b2 = (const float*)d_in[4];
  const float* Wg = (const float*)d_in[5];
  const float* bg = (const float*)d_in[6];
  float* out = (float*)d_out;

  char* ws = (char*)d_ws;
  int*            counts  = (int*)(ws);
  int*            tok_idx = (int*)(ws + 1024);
  float*          tok_w   = (float*)(ws + 263168);
  unsigned short* xb      = (unsigned short*)(ws + 525312);
  unsigned short* w1t     = (unsigned short*)(ws + 525312 + 16777216ull);
  unsigned short* w2t     = (unsigned short*)(ws + 525312 + 2ull * 16777216ull);
  unsigned short* hb      = (unsigned short*)(ws + 525312 + 3ull * 16777216ull);
  size_t gate_off = 525312 + 3ull * 16777216ull + 37748736ull;  // 88605696
  int*            tok_top = (int*)(ws + gate_off);
  float2*         tok_wts = (float2*)(ws + gate_off + 32768);

  hipMemsetAsync(d_out, 0, (size_t)N_TOK * DIM * sizeof(float), stream);

  prep_kernel<<<4096 + 2048, 256, 0, stream>>>(W1, W2, w1t, w2t,
                                               x, Wg, bg, tok_top, tok_wts, xb);
  gate2_kernel<<<NUM_E, 1024, 0, stream>>>(tok_top, tok_wts, counts, tok_idx, tok_w);
  // y = global 256-row m-tile id; worst case 64 + 8 = 72 tiles
  moe_gemm_kernel<true><<<dim3(4, 72), 512, 0, stream>>>(
      xb, w1t, b1, counts, tok_idx, tok_w, hb, nullptr);
  moe_gemm_kernel<false><<<dim3(4, 72), 512, 0, stream>>>(
      hb, w2t, b2, counts, tok_idx, tok_w, nullptr, out);
}

// Round 4
// 368.407 us; speedup vs baseline: 1.0757x; 1.0757x over previous
//
#include <hip/hip_runtime.h>

#define NUM_E 8
#define N_TOK 8192
#define DIM 1024

typedef __attribute__((ext_vector_type(8))) short short8;
typedef __attribute__((ext_vector_type(4))) float f32x4;

// fp32 -> bf16 round-to-nearest-even
__device__ __forceinline__ unsigned short f2bf(float f) {
  unsigned int u = __float_as_uint(f);
  u = (u + 0x7fffu + ((u >> 16) & 1u)) >> 16;
  return (unsigned short)u;
}

// async global->LDS, 16B per lane. Global addr is per-lane; LDS dest is
// wave-uniform base + lane*16 (m104/m108 semantics).
__device__ __forceinline__ void async16(const unsigned short* g, unsigned short* l) {
  __builtin_amdgcn_global_load_lds((const __attribute__((address_space(1))) void*)g,
                                   (__attribute__((address_space(3))) void*)l,
                                   16, 0, 0);
}

// ---------------- prep: fused W-transpose-convert + gating ----------------
// blocks [0,4096): W[e][k][n] fp32 -> WT[e][n][k] bf16, 64x64 LDS transpose.
// blocks [4096,6144): gating (4 tokens/block) + x->bf16 conversion.
__global__ __launch_bounds__(256) void prep_kernel(
    const float* __restrict__ W1, const float* __restrict__ W2,
    unsigned short* __restrict__ W1T, unsigned short* __restrict__ W2T,
    const float* __restrict__ x, const float* __restrict__ Wg,
    const float* __restrict__ bg, int* __restrict__ tok_top,
    float2* __restrict__ tok_wts, unsigned short* __restrict__ xb) {
  __shared__ float s[64][65];
  if (blockIdx.x < 4096) {
    const int bx  = blockIdx.x;          // 16 mats * 16 ktiles * 16 ntiles
    const int mat = bx >> 8;
    const int tk  = (bx >> 4) & 15;
    const int tn  = bx & 15;
    const float* src;
    unsigned short* dst;
    if (mat < 8) { src = W1 + (size_t)mat * (DIM * DIM); dst = W1T + (size_t)mat * (DIM * DIM); }
    else         { src = W2 + (size_t)(mat - 8) * (DIM * DIM); dst = W2T + (size_t)(mat - 8) * (DIM * DIM); }
    const int k0 = tk * 64, n0 = tn * 64;
    const int t = threadIdx.x;
    {
      const int rr = t >> 4;
      const int c4 = (t & 15) * 4;
#pragma unroll
      for (int i = 0; i < 4; ++i) {
        const int k = i * 16 + rr;
        float4 v = *(const float4*)&src[(size_t)(k0 + k) * DIM + n0 + c4];
        s[c4 + 0][k] = v.x; s[c4 + 1][k] = v.y;
        s[c4 + 2][k] = v.z; s[c4 + 3][k] = v.w;
      }
    }
    __syncthreads();
    {
      const int kq = (t & 7) * 8;
      const int nn = t >> 3;
#pragma unroll
      for (int r = 0; r < 2; ++r) {
        const int n = r * 32 + nn;
        union { unsigned short us[8]; uint4 v; } o;
#pragma unroll
        for (int j = 0; j < 8; ++j) o.us[j] = f2bf(s[n][kq + j]);
        *(uint4*)(dst + (size_t)(n0 + n) * DIM + k0 + kq) = o.v;
      }
    }
  } else {
    const int wave = threadIdx.x >> 6;
    const int lane = threadIdx.x & 63;
    const int n = (blockIdx.x - 4096) * 4 + wave;
    const float4* xr = (const float4*)(x + (size_t)n * DIM);
    unsigned short* xbr = xb + (size_t)n * DIM;
    float acc[NUM_E];
#pragma unroll
    for (int e = 0; e < NUM_E; ++e) acc[e] = 0.f;
#pragma unroll
    for (int it = 0; it < 4; ++it) {
      float4 xv = xr[it * 64 + lane];
      const float4* wr = (const float4*)Wg + (size_t)(it * 256 + lane * 4) * 2;
      float xs[4] = {xv.x, xv.y, xv.z, xv.w};
      union { unsigned short u[4]; uint2 v; } oo;
      oo.u[0] = f2bf(xv.x); oo.u[1] = f2bf(xv.y);
      oo.u[2] = f2bf(xv.z); oo.u[3] = f2bf(xv.w);
      *(uint2*)(xbr + it * 256 + lane * 4) = oo.v;
#pragma unroll
      for (int dd = 0; dd < 4; ++dd) {
        float4 wa = wr[dd * 2 + 0];
        float4 wb = wr[dd * 2 + 1];
        acc[0] += xs[dd] * wa.x; acc[1] += xs[dd] * wa.y;
        acc[2] += xs[dd] * wa.z; acc[3] += xs[dd] * wa.w;
        acc[4] += xs[dd] * wb.x; acc[5] += xs[dd] * wb.y;
        acc[6] += xs[dd] * wb.z; acc[7] += xs[dd] * wb.w;
      }
    }
#pragma unroll
    for (int e = 0; e < NUM_E; ++e)
#pragma unroll
      for (int off = 32; off > 0; off >>= 1)
        acc[e] += __shfl_down(acc[e], off);
    if (lane == 0) {
      float p[NUM_E];
      float mx = -1e30f;
#pragma unroll
      for (int e = 0; e < NUM_E; ++e) { p[e] = acc[e] + bg[e]; mx = fmaxf(mx, p[e]); }
      float ss = 0.f;
#pragma unroll
      for (int e = 0; e < NUM_E; ++e) { p[e] = expf(p[e] - mx); ss += p[e]; }
      float inv = 1.f / ss;
      int i0 = 0;
#pragma unroll
      for (int e = 1; e < NUM_E; ++e) if (p[e] > p[i0]) i0 = e;
      int i1 = (i0 == 0) ? 1 : 0;
#pragma unroll
      for (int e = 0; e < NUM_E; ++e) if (e != i0 && p[e] > p[i1]) i1 = e;
      tok_top[n] = i0 | (i1 << 8);
      tok_wts[n] = make_float2(p[i0] * inv, p[i1] * inv);
    }
  }
}

// gate2: one block per expert; block-wide exclusive scan compacts token lists.
__global__ __launch_bounds__(1024) void gate2_kernel(const int* __restrict__ tok_top,
                                                     const float2* __restrict__ tok_wts,
                                                     int* __restrict__ counts,
                                                     int* __restrict__ tok_idx,
                                                     float* __restrict__ tok_w) {
  const int e = blockIdx.x;
  const int t = threadIdx.x;
  const int lane = t & 63;
  const int wave = t >> 6;
  __shared__ int wsum[16];
  __shared__ int blocktot;
  int match[8];
  float w[8];
  int cnt = 0;
#pragma unroll
  for (int j = 0; j < 8; ++j) {
    int n = t * 8 + j;
    int top = tok_top[n];
    float2 ww = tok_wts[n];
    bool m0 = (top & 0xff) == e;
    bool m1 = ((top >> 8) & 0xff) == e;
    match[j] = (m0 || m1) ? 1 : 0;
    w[j] = m0 ? ww.x : ww.y;
    cnt += match[j];
  }
  int inc = cnt;
#pragma unroll
  for (int off = 1; off < 64; off <<= 1) {
    int v = __shfl_up(inc, off);
    if (lane >= off) inc += v;
  }
  if (lane == 63) wsum[wave] = inc;
  __syncthreads();
  if (t < 16) {
    int v = wsum[t];
    int s = v;
#pragma unroll
    for (int off = 1; off < 16; off <<= 1) {
      int u = __shfl_up(s, off);
      if (lane >= off) s += u;
    }
    wsum[t] = s - v;
    if (t == 15) blocktot = s;
  }
  __syncthreads();
  int slot = wsum[wave] + inc - cnt;
#pragma unroll
  for (int j = 0; j < 8; ++j) {
    if (match[j]) {
      tok_idx[e * N_TOK + slot] = t * 8 + j;
      tok_w[e * N_TOK + slot] = w[j];
      slot++;
    }
  }
  if (t == 0) counts[e] = blocktot;
}

// ---------------- expert GEMMs ----------------
// R8 = R4's proven 128x128 / BK=64 single-buffer loop (115us, 0 bank conflicts)
// with two additions:
//  * XCD-chunked block mapping: 1D grid 1088 = 8 xcd * 17 mt * 8 nt;
//    xcd = bid&7 (dispatch round-robin), mt = 17*xcd + (bid>>6), nt = (bid>>3)&7.
//    The 8 n-blocks of one m-tile are consecutive on ONE XCD -> A panel fetched
//    once into that XCD's L2 (was 8 XCDs x 8 fetches); B expert panel (~2.1MB)
//    stays L2-resident across the chunk. Goal: vmcnt(0)-drain latency drops from
//    HBM-miss (~900cy) to L2-hit (~200-300cy), which is the measured bottleneck
//    (MfmaUtil 12%, HBM 30% of achievable -> latency-bound).
//  * __launch_bounds__(256,4): 33KB LDS x4 = 132KB <= 160KB, VGPR 56+64acc=120
//    <= 128 -> 4 blocks/CU (16 waves) for more cross-block stall overlap.
// LDS layout per plane: 8 chunks x (16 rows x 32 k) lane-linear: conflict-free
// for both async16 writes and ds_read_b128 fragment reads (measured 0).

template <bool FC1>
__global__ __launch_bounds__(256, 4) void moe_gemm_kernel(
    const unsigned short* __restrict__ A_src,  // FC1: x_bf16 ; FC2: h
    const unsigned short* __restrict__ wT,     // [E][1024 n][1024 k] bf16
    const float* __restrict__ bias,            // [E][1024]
    const int* __restrict__ counts,
    const int* __restrict__ tok_idx,           // [E][8192]
    const float* __restrict__ tok_w,           // [E][8192]
    unsigned short* __restrict__ h_out,        // FC1 dest (compacted rows)
    float* __restrict__ out)                   // FC2 dest (atomic accumulate)
{
  // ---- XCD-chunked work mapping ----
  const int bid = blockIdx.x;
  const int xcd = bid & 7;
  const int mt  = xcd * 17 + (bid >> 6);   // global m-tile id, 0..135
  const int nt  = (bid >> 3) & 7;          // n-tile id, 0..7

  // ---- tile table from counts (all padding handled by early-exit) ----
  int e = -1, m0 = 0, base = 0;
  {
    int acc_tiles = 0, acc_rows = 0;
#pragma unroll
    for (int i = 0; i < NUM_E; ++i) {
      int c = counts[i];
      int t = (c + 127) >> 7;
      if (mt >= acc_tiles && mt < acc_tiles + t) {
        e = i; m0 = (mt - acc_tiles) * 128; base = acc_rows;
      }
      acc_tiles += t;
      acc_rows += t * 128;
    }
  }
  if (e < 0) return;
  const int count = counts[e];
  const int n0 = nt * 128;

  const int tid  = threadIdx.x;
  const int wave = tid >> 6;
  const int lane = tid & 63;
  const int l15  = lane & 15;
  const int quad = lane >> 4;
  const int wm   = wave & 1;
  const int wn   = wave >> 1;

  __shared__ unsigned short sA[2 * 4096];  // [plane][chunk*512 + lane*8]
  __shared__ unsigned short sB[2 * 4096];
  __shared__ int   s_tok[128];
  __shared__ float s_w[128];

  if (!FC1 && tid < 128) {
    int slot = m0 + tid;
    int cs = slot < count ? slot : count - 1;
    s_tok[tid] = tok_idx[e * N_TOK + cs];
    s_w[tid]   = slot < count ? tok_w[e * N_TOK + slot] : 0.f;
  }

  // this lane's two A-staging source rows (chunks 2*wave, 2*wave+1)
  const int r0 = 32 * wave + l15;
  const int r1 = r0 + 16;
  size_t aOff0, aOff1;
  if (FC1) {  // gather token rows from x
    int s0 = m0 + r0; s0 = s0 < count ? s0 : count - 1;
    int s1 = m0 + r1; s1 = s1 < count ? s1 : count - 1;
    aOff0 = (size_t)tok_idx[e * N_TOK + s0] * DIM;
    aOff1 = (size_t)tok_idx[e * N_TOK + s1] * DIM;
  } else {    // contiguous compacted h rows
    aOff0 = (size_t)(base + m0 + r0) * DIM;
    aOff1 = (size_t)(base + m0 + r1) * DIM;
  }
  const unsigned short* wte = wT + (size_t)e * DIM * DIM;
  const size_t bOff0 = (size_t)(n0 + r0) * DIM;
  const size_t bOff1 = (size_t)(n0 + r1) * DIM;
  const int kl = quad * 8;
  const int c0 = (2 * wave + 0) * 512;
  const int c1 = (2 * wave + 1) * 512;

  const f32x4 vzero = {0.f, 0.f, 0.f, 0.f};
  f32x4 acc[4][4];
#pragma unroll
  for (int i = 0; i < 4; ++i)
#pragma unroll
    for (int j = 0; j < 4; ++j) acc[i][j] = vzero;

  for (int k0 = 0; k0 < DIM; k0 += 64) {
    // stage both 32-wide planes of the 64-wide K-tile (8 async16/lane)
    async16(A_src + aOff0 + k0 + kl,      &sA[c0]);
    async16(A_src + aOff1 + k0 + kl,      &sA[c1]);
    async16(A_src + aOff0 + k0 + 32 + kl, &sA[4096 + c0]);
    async16(A_src + aOff1 + k0 + 32 + kl, &sA[4096 + c1]);
    async16(wte + bOff0 + k0 + kl,        &sB[c0]);
    async16(wte + bOff1 + k0 + kl,        &sB[c1]);
    async16(wte + bOff0 + k0 + 32 + kl,   &sB[4096 + c0]);
    async16(wte + bOff1 + k0 + 32 + kl,   &sB[4096 + c1]);
    __syncthreads();  // emits vmcnt(0) drain + barrier (m97 structure)
#pragma unroll
    for (int s = 0; s < 2; ++s) {
      short8 af[4], bfr[4];
#pragma unroll
      for (int i = 0; i < 4; ++i)
        af[i] = *(const short8*)&sA[s * 4096 + (wm * 4 + i) * 512 + lane * 8];
#pragma unroll
      for (int j = 0; j < 4; ++j)
        bfr[j] = *(const short8*)&sB[s * 4096 + (wn * 4 + j) * 512 + lane * 8];
#pragma unroll
      for (int i = 0; i < 4; ++i)
#pragma unroll
        for (int j = 0; j < 4; ++j)
          acc[i][j] = __builtin_amdgcn_mfma_f32_16x16x32_bf16(af[i], bfr[j], acc[i][j], 0, 0, 0);
    }
    __syncthreads();  // WAR guard before next stage overwrites
  }

  float bv[4];
#pragma unroll
  for (int j = 0; j < 4; ++j)
    bv[j] = bias[e * DIM + n0 + (wn * 4 + j) * 16 + l15];

  // C/D layout (m89-verified): col = lane&15, row = quad*4 + reg
  if (FC1) {
#pragma unroll
    for (int i = 0; i < 4; ++i) {
      const int rbase = (wm * 4 + i) * 16 + quad * 4;
#pragma unroll
      for (int r = 0; r < 4; ++r) {
        const int slot = m0 + rbase + r;
        if (slot < count) {
          unsigned short* hp = h_out + (size_t)(base + slot) * DIM + n0;
#pragma unroll
          for (int j = 0; j < 4; ++j) {
            float v = acc[i][j][r] + bv[j];
            v = v > 0.f ? v : 0.f;
            hp[(wn * 4 + j) * 16 + l15] = f2bf(v);
          }
        }
      }
    }
  } else {
#pragma unroll
    for (int i = 0; i < 4; ++i) {
      const int rbase = (wm * 4 + i) * 16 + quad * 4;
#pragma unroll
      for (int r = 0; r < 4; ++r) {
        const int slot = m0 + rbase + r;
        if (slot < count) {
          const int rl = rbase + r;
          const int tok = s_tok[rl];
          const float w = s_w[rl];
          float* op = out + (size_t)tok * DIM + n0;
#pragma unroll
          for (int j = 0; j < 4; ++j) {
            float v = acc[i][j][r] + bv[j];
            atomicAdd(&op[(wn * 4 + j) * 16 + l15], w * v);
          }
        }
      }
    }
  }
}

// ---------------- launch ----------------
// ws layout (bytes):
//   0        counts[8]
//   1024     tok_idx [8][8192] int    (256 KB)
//   263168   tok_w   [8][8192] float  (256 KB)
//   525312   x_bf16  [8192][1024]     (16 MB)
//   +16MB    W1T bf16 [8][1024][1024] (16 MB)
//   +32MB    W2T bf16                 (16 MB)
//   +48MB    h bf16, 17408 rows x1024 (34 MB)  (max padded rows 17400)
//   +~82.5MB tok_top int[8192] (32KB), tok_wts float2[8192] (64KB)

extern "C" void kernel_launch(void* const* d_in, const int* in_sizes, int n_in,
                              void* d_out, int out_size, void* d_ws, size_t ws_size,
                              hipStream_t stream) {
  const float* x  = (const float*)d_in[0];
  const float* W1 = (const float*)d_in[1];
  const float* b1 = (const float*)d_in[2];
  const float* W2 = (const float*)d_in[3];
  const float* b2 = (const float*)d_in[4];
  const float* Wg = (const float*)d_in[5];
  const float* bg = (const float*)d_in[6];
  float* out = (float*)d_out;

  char* ws = (char*)d_ws;
  int*            counts  = (int*)(ws);
  int*            tok_idx = (int*)(ws + 1024);
  float*          tok_w   = (float*)(ws + 263168);
  unsigned short* xb      = (unsigned short*)(ws + 525312);
  unsigned short* w1t     = (unsigned short*)(ws + 525312 + 16777216ull);
  unsigned short* w2t     = (unsigned short*)(ws + 525312 + 2ull * 16777216ull);
  unsigned short* hb      = (unsigned short*)(ws + 525312 + 3ull * 16777216ull);
  size_t gate_off = 525312 + 3ull * 16777216ull + 35651584ull;
  int*            tok_top = (int*)(ws + gate_off);
  float2*         tok_wts = (float2*)(ws + gate_off + 32768);

  hipMemsetAsync(d_out, 0, (size_t)N_TOK * DIM * sizeof(float), stream);

  prep_kernel<<<4096 + 2048, 256, 0, stream>>>(W1, W2, w1t, w2t,
                                               x, Wg, bg, tok_top, tok_wts, xb);
  gate2_kernel<<<NUM_E, 1024, 0, stream>>>(tok_top, tok_wts, counts, tok_idx, tok_w);
  // 1D grid: 8 xcd chunks x 17 m-tiles x 8 n-tiles = 1088 blocks
  moe_gemm_kernel<true><<<1088, 256, 0, stream>>>(
      xb, w1t, b1, counts, tok_idx, tok_w, hb, nullptr);
  moe_gemm_kernel<false><<<1088, 256, 0, stream>>>(
      hb, w2t, b2, counts, tok_idx, tok_w, nullptr, out);
}